// Round 8
// baseline (314.899 us; speedup 1.0000x reference)
//
#include <hip/hip_runtime.h>
#include <math.h>

#define NROWS 4096
#define VCOLS 32000
#define NV4   (VCOLS / 4)     // 8000 float4 per row

typedef float f32x4 __attribute__((ext_vector_type(4)));

// Constants from reference: LS=0.1, CONF=0.9, SM=0.1/31999
constexpr float CONF_F   = 0.9f;
constexpr float SM_F     = 0.1f / 31999.0f;          // 3.1250977e-06
constexpr float KL_CONST = -1.36242896f;             // 0.9*ln(0.9) + 0.1*ln(SM)
constexpr float COEF_T   = CONF_F - SM_F;            // weight on logp[target]

// ---- kernel 1: init first-occurrence table + ticket counter ----
__global__ void k_init(int* __restrict__ ft32, int* __restrict__ ticket) {
    int v = blockIdx.x * blockDim.x + threadIdx.x;
    if (v < VCOLS) ft32[v] = NROWS;     // sentinel: never a candidate
    if (v == 0)    *ticket = 0;
}

// ---- kernel 2: first occurrence via atomicMin ----
__global__ void k_scatter(const int* __restrict__ target,
                          int* __restrict__ ft32) {
    int j = blockIdx.x * blockDim.x + threadIdx.x;
    if (j < NROWS) {
        int t  = target[j];
        int tc = (t != -1) ? t : 0;     // tgt = where(valid, target, PAD)
        // token 0 (PAD) excluded from neg targets (neg[:,0]=0): never mark.
        if (tc != 0) atomicMin(&ft32[tc], j);
    }
}

// ---- kernel 3: pack table to u16 (values <= 4096) ----
__global__ void k_pack(const int* __restrict__ ft32,
                       unsigned short* __restrict__ ft16) {
    int v = blockIdx.x * blockDim.x + threadIdx.x;
    if (v < VCOLS) ft16[v] = (unsigned short)ft32[v];
}

// ---- kernel 4: fused single-pass row kernel (256 thr, x4 up-front loads) ----
// One block per row, one coalesced sweep: branchless online softmax stats
// (one rescale per 16 floats) + sum of logits + gold logit + candidate
// logits into deterministic LDS slots cand[ft16[v]] (candidate iff
// ft16[v] < i, v != tgt_i; ft16[0]==NROWS). The last block to finish also
// performs the final reduction (ticket + device-scope fences).
__global__ __launch_bounds__(256)
void k_main(const float* __restrict__ X,
            const int*   __restrict__ target,
            const unsigned short* __restrict__ ft16,
            float* __restrict__ kl_rows,
            float* __restrict__ custom_rows,
            int*   __restrict__ ticket,
            float* __restrict__ out) {
    const int i   = blockIdx.x;
    const int tid = threadIdx.x;

    __shared__ float cand[NROWS];       // candidate logits by first-occ pos (16 KB)
    __shared__ float rm[256], rz[256], rs[256];
    __shared__ float s_logZ, s_xt;
    __shared__ int   s_last;

    const int t = target[i];
    const bool valid = (t != -1);

    if (valid) {
        const int    mytgt = t;                     // valid -> tclean == target
        const float* row   = X + (size_t)i * VCOLS;

        if (tid == 0) s_xt = row[mytgt];            // gold logit, once
        for (int j = tid; j < i; j += 256) cand[j] = -INFINITY;
        __syncthreads();

        const f32x4* row4 = (const f32x4*)row;      // 16B aligned (stride 128000B)
        const int2*  ft2  = (const int2*)ft16;      // 4 u16 per float4

        float m = -INFINITY, Z = 0.0f, sx = 0.0f;

#define MAX4(xx_) fmaxf(fmaxf((xx_).x, (xx_).y), fmaxf((xx_).z, (xx_).w))
#define PROC(xx_, ff_, ee_) do {                                              \
        Z += __expf((xx_).x - m) + __expf((xx_).y - m)                        \
           + __expf((xx_).z - m) + __expf((xx_).w - m);                       \
        sx += ((xx_).x + (xx_).y) + ((xx_).z + (xx_).w);                      \
        int base_ = (ee_) * 4;                                                \
        int a0_ = (ff_).x & 0xFFFF, a1_ = (int)(((unsigned)(ff_).x) >> 16);   \
        int a2_ = (ff_).y & 0xFFFF, a3_ = (int)(((unsigned)(ff_).y) >> 16);   \
        unsigned d_ = (unsigned)(mytgt - base_);                              \
        if (a0_ < i && d_ != 0u) cand[a0_] = (xx_).x;                         \
        if (a1_ < i && d_ != 1u) cand[a1_] = (xx_).y;                         \
        if (a2_ < i && d_ != 2u) cand[a2_] = (xx_).z;                         \
        if (a3_ < i && d_ != 3u) cand[a3_] = (xx_).w;                         \
    } while (0)

        for (int eb = tid; eb < NV4; eb += 1024) {
            const bool v1 = (eb +  256) < NV4;
            const bool v2 = (eb +  512) < NV4;
            const bool v3 = (eb +  768) < NV4;
            f32x4 x0, x1, x2, x3;
            int2  f0, f1, f2, f3;
            x0 = row4[eb];                 f0 = ft2[eb];
            if (v1) { x1 = row4[eb + 256]; f1 = ft2[eb + 256]; }
            if (v2) { x2 = row4[eb + 512]; f2 = ft2[eb + 512]; }
            if (v3) { x3 = row4[eb + 768]; f3 = ft2[eb + 768]; }

            float cm = MAX4(x0);
            if (v1) cm = fmaxf(cm, MAX4(x1));
            if (v2) cm = fmaxf(cm, MAX4(x2));
            if (v3) cm = fmaxf(cm, MAX4(x3));
            // branchless rescale: one extra exp per 16 floats, no control flow
            float mn = fmaxf(m, cm);
            Z *= __expf(m - mn);
            m  = mn;

            PROC(x0, f0, eb);
            if (v1) PROC(x1, f1, eb + 256);
            if (v2) PROC(x2, f2, eb + 512);
            if (v3) PROC(x3, f3, eb + 768);
        }
#undef PROC
#undef MAX4

        rm[tid] = m; rz[tid] = Z; rs[tid] = sx;
        __syncthreads();
        for (int s = 128; s > 0; s >>= 1) {
            if (tid < s) {
                float m2 = rm[tid + s], z2 = rz[tid + s];
                float mm = fmaxf(rm[tid], m2);
                rz[tid]  = rz[tid] * __expf(rm[tid] - mm) + z2 * __expf(m2 - mm);
                rm[tid]  = mm;
                rs[tid] += rs[tid + s];
            }
            __syncthreads();
        }
        if (tid == 0) {
            float logZ    = rm[0] + __logf(rz[0]);
            s_logZ        = logZ;
            float logp_t  = s_xt - logZ;
            float sumlogp = rs[0] - (float)VCOLS * logZ;   // sum_j logp[i,j]
            kl_rows[i] = KL_CONST - COEF_T * logp_t - SM_F * sumlogp;
        }
        __syncthreads();
        const float logZ = s_logZ;

        // ---- unlikelihood tail over the candidate list ----
        float acc = 0.0f;
        for (int j = tid; j < i; j += 256) {
            float xv = cand[j];                 // -inf -> p=0 -> term 0
            float p  = __expf(xv - logZ);
            float om = fmaxf(1.0f - p, 1e-5f);
            acc -= __logf(om);
        }
        rs[tid] = acc;
        __syncthreads();
        for (int s = 128; s > 0; s >>= 1) {
            if (tid < s) rs[tid] += rs[tid + s];
            __syncthreads();
        }
        if (tid == 0) custom_rows[i] = rs[0];
    } else {
        if (tid == 0) { kl_rows[i] = 0.0f; custom_rows[i] = 0.0f; }
    }

    // ---- ticket: last block to finish does the final reduction ----
    __syncthreads();
    if (tid == 0) {
        __threadfence();                          // publish row results
        s_last = (atomicAdd(ticket, 1) == NROWS - 1);
    }
    __syncthreads();
    if (s_last) {
        __threadfence();                          // acquire others' results
        float L = 0.0f, C = 0.0f, Nn = 0.0f;
        for (int j = tid; j < NROWS; j += 256) {
            L += kl_rows[j];
            C += custom_rows[j];
            int tj = target[j];
            if (tj != -1 && tj != 0) Nn += 1.0f;  // valid & (tgt != PAD)
        }
        rm[tid] = L; rz[tid] = C; rs[tid] = Nn;
        __syncthreads();
        for (int s = 128; s > 0; s >>= 1) {
            if (tid < s) {
                rm[tid] += rm[tid + s];
                rz[tid] += rz[tid + s];
                rs[tid] += rs[tid + s];
            }
            __syncthreads();
        }
        if (tid == 0) {
            float norm = rs[0];
            out[0] = rm[0] / norm + 0.1f * rz[0] / norm;
        }
    }
}

extern "C" void kernel_launch(void* const* d_in, const int* in_sizes, int n_in,
                              void* d_out, int out_size, void* d_ws, size_t ws_size,
                              hipStream_t stream) {
    const float* X      = (const float*)d_in[0];   // (N, V) float32
    const int*   target = (const int*)d_in[1];     // (N,)   int32
    float*       out    = (float*)d_out;

    char* ws = (char*)d_ws;
    int*            ft32        = (int*)           (ws);                    // 128000 B
    unsigned short* ft16        = (unsigned short*)(ws + 128000);           //  64000 B
    float*          kl_rows     = (float*)         (ws + 192000);           //  16384 B
    float*          custom_rows = (float*)         (ws + 192000 + 16384);   //  16384 B
    int*            ticket      = (int*)           (ws + 192000 + 32768);   //      4 B

    k_init   <<<(VCOLS + 255) / 256, 256, 0, stream>>>(ft32, ticket);
    k_scatter<<<(NROWS + 255) / 256, 256, 0, stream>>>(target, ft32);
    k_pack   <<<(VCOLS + 255) / 256, 256, 0, stream>>>(ft32, ft16);
    k_main   <<<NROWS,               256, 0, stream>>>(X, target, ft16,
                                                       kl_rows, custom_rows,
                                                       ticket, out);
}

// Round 9
// 109.976 us; speedup vs baseline: 2.8634x; 2.8634x over previous
//
#include <hip/hip_runtime.h>
#include <math.h>

#define NROWS 4096
#define VCOLS 32000
#define NV4   (VCOLS / 4)     // 8000 float4 per row

typedef float f32x4 __attribute__((ext_vector_type(4)));

// Constants from reference: LS=0.1, CONF=0.9, SM=0.1/31999
constexpr float CONF_F   = 0.9f;
constexpr float SM_F     = 0.1f / 31999.0f;          // 3.1250977e-06
constexpr float KL_CONST = -1.36242896f;             // 0.9*ln(0.9) + 0.1*ln(SM)
constexpr float COEF_T   = CONF_F - SM_F;            // weight on logp[target]

// ---- kernel 1: init first-occurrence table ----
__global__ void k_init(int* __restrict__ ft32) {
    int v = blockIdx.x * blockDim.x + threadIdx.x;
    if (v < VCOLS) ft32[v] = NROWS;     // sentinel: never a candidate
}

// ---- kernel 2: first occurrence via atomicMin ----
__global__ void k_scatter(const int* __restrict__ target,
                          int* __restrict__ ft32) {
    int j = blockIdx.x * blockDim.x + threadIdx.x;
    if (j < NROWS) {
        int t  = target[j];
        int tc = (t != -1) ? t : 0;     // tgt = where(valid, target, PAD)
        // token 0 (PAD) excluded from neg targets (neg[:,0]=0): never mark.
        if (tc != 0) atomicMin(&ft32[tc], j);
    }
}

// ---- kernel 3: pack table to u16 (values <= 4096) ----
__global__ void k_pack(const int* __restrict__ ft32,
                       unsigned short* __restrict__ ft16) {
    int v = blockIdx.x * blockDim.x + threadIdx.x;
    if (v < VCOLS) ft16[v] = (unsigned short)ft32[v];
}

// ---- kernel 4: fused single-pass row kernel, software-pipelined ----
// One block per row. Rotating 2-slot prefetch: iteration k+1's 4 loads are
// issued BEFORE iteration k's registers are consumed -> 4 loads in flight
// per wave (the R3 "up-front load" version compiled to serialized loads,
// VGPR_Count=24 — this structure forces the batch to stay in registers).
// Branchless online rescale once per 8 floats. Candidate logits go to
// deterministic LDS slots cand[ft16[v]] (unique writer per slot).
__global__ __launch_bounds__(256)
void k_main(const float* __restrict__ X,
            const int*   __restrict__ target,
            const unsigned short* __restrict__ ft16,
            float* __restrict__ kl_rows,
            float* __restrict__ custom_rows) {
    const int i   = blockIdx.x;
    const int tid = threadIdx.x;

    __shared__ float cand[NROWS];       // candidate logits by first-occ pos (16 KB)
    __shared__ float rm[256], rz[256], rs[256];
    __shared__ float s_logZ, s_xt;

    const int t = target[i];
    if (t == -1) {
        if (tid == 0) { kl_rows[i] = 0.0f; custom_rows[i] = 0.0f; }
        return;
    }
    const int    mytgt = t;                         // valid -> tgt == target
    const float* row   = X + (size_t)i * VCOLS;

    if (tid == 0) s_xt = row[mytgt];                // gold logit, once
    for (int j = tid; j < i; j += 256) cand[j] = -INFINITY;
    __syncthreads();

    const f32x4* row4 = (const f32x4*)row;          // 16B aligned (stride 128000B)
    const int2*  ft2  = (const int2*)ft16;          // 4 u16 per f32x4

    float m = -INFINITY, Z = 0.0f, sx = 0.0f;

#define MAX4(xx_) fmaxf(fmaxf((xx_).x, (xx_).y), fmaxf((xx_).z, (xx_).w))
#define SCAT(xx_, ff_, ee_) do {                                              \
        int base_ = (ee_) * 4;                                                \
        int a0_ = (ff_).x & 0xFFFF, a1_ = (int)(((unsigned)(ff_).x) >> 16);   \
        int a2_ = (ff_).y & 0xFFFF, a3_ = (int)(((unsigned)(ff_).y) >> 16);   \
        unsigned d_ = (unsigned)(mytgt - base_);                              \
        if (a0_ < i && d_ != 0u) cand[a0_] = (xx_).x;                         \
        if (a1_ < i && d_ != 1u) cand[a1_] = (xx_).y;                         \
        if (a2_ < i && d_ != 2u) cand[a2_] = (xx_).z;                         \
        if (a3_ < i && d_ != 3u) cand[a3_] = (xx_).w;                         \
    } while (0)
#define CHUNK(xa_, fa_, xb_, fb_, ea_) do {                                   \
        float cm_ = fmaxf(MAX4(xa_), MAX4(xb_));                              \
        float mn_ = fmaxf(m, cm_);                                            \
        Z *= __expf(m - mn_);            /* branchless rescale */             \
        m  = mn_;                                                             \
        Z += __expf((xa_).x - m) + __expf((xa_).y - m)                        \
           + __expf((xa_).z - m) + __expf((xa_).w - m)                        \
           + __expf((xb_).x - m) + __expf((xb_).y - m)                        \
           + __expf((xb_).z - m) + __expf((xb_).w - m);                       \
        sx += ((xa_).x + (xa_).y) + ((xa_).z + (xa_).w)                       \
            + ((xb_).x + (xb_).y) + ((xb_).z + (xb_).w);                      \
        SCAT(xa_, fa_, (ea_));                                                \
        SCAT(xb_, fb_, (ea_) + 256);                                          \
    } while (0)

    // prologue: first pair resident (tid+256 < 8000 always)
    int e = tid;
    f32x4 xa = row4[e];        int2 fa = ft2[e];
    f32x4 xb = row4[e + 256];  int2 fb = ft2[e + 256];
    int en = e + 512;

    while (en + 256 < NV4) {            // next full pair exists
        // issue next pair's loads BEFORE consuming current registers
        f32x4 xc = row4[en];        int2 fc = ft2[en];
        f32x4 xd = row4[en + 256];  int2 fd = ft2[en + 256];
        CHUNK(xa, fa, xb, fb, e);       // compute overlaps the 4 loads
        xa = xc; fa = fc; xb = xd; fb = fd;
        e = en; en += 512;
    }
    CHUNK(xa, fa, xb, fb, e);           // last resident pair

    for (; en < NV4; en += 256) {       // tail singles (0..2 per thread)
        f32x4 x_ = row4[en];  int2 f_ = ft2[en];
        float m4 = MAX4(x_);
        float mn = fmaxf(m, m4);
        Z *= __expf(m - mn);
        m  = mn;
        Z += __expf(x_.x - m) + __expf(x_.y - m)
           + __expf(x_.z - m) + __expf(x_.w - m);
        sx += (x_.x + x_.y) + (x_.z + x_.w);
        SCAT(x_, f_, en);
    }
#undef CHUNK
#undef SCAT
#undef MAX4

    rm[tid] = m; rz[tid] = Z; rs[tid] = sx;
    __syncthreads();
    for (int s = 128; s > 0; s >>= 1) {
        if (tid < s) {
            float m2 = rm[tid + s], z2 = rz[tid + s];
            float mm = fmaxf(rm[tid], m2);
            rz[tid]  = rz[tid] * __expf(rm[tid] - mm) + z2 * __expf(m2 - mm);
            rm[tid]  = mm;
            rs[tid] += rs[tid + s];
        }
        __syncthreads();
    }
    if (tid == 0) {
        float logZ    = rm[0] + __logf(rz[0]);
        s_logZ        = logZ;
        float logp_t  = s_xt - logZ;
        float sumlogp = rs[0] - (float)VCOLS * logZ;   // sum_j logp[i,j]
        kl_rows[i] = KL_CONST - COEF_T * logp_t - SM_F * sumlogp;
    }
    __syncthreads();
    const float logZ = s_logZ;

    // ---- unlikelihood tail over the candidate list ----
    float acc = 0.0f;
    for (int j = tid; j < i; j += 256) {
        float xv = cand[j];                 // -inf -> p=0 -> term 0
        float p  = __expf(xv - logZ);
        float om = fmaxf(1.0f - p, 1e-5f);
        acc -= __logf(om);
    }
    rs[tid] = acc;
    __syncthreads();
    for (int s = 128; s > 0; s >>= 1) {
        if (tid < s) rs[tid] += rs[tid + s];
        __syncthreads();
    }
    if (tid == 0) custom_rows[i] = rs[0];
}

// ---- kernel 5: deterministic final reduction ----
__global__ __launch_bounds__(1024)
void k_final(const float* __restrict__ kl_rows,
             const float* __restrict__ custom_rows,
             const int*   __restrict__ target,
             float* __restrict__ out) {
    __shared__ float sl[1024], sc[1024], sn[1024];
    int tid = threadIdx.x;
    float L = 0.0f, C = 0.0f, Nn = 0.0f;
    for (int j = tid; j < NROWS; j += 1024) {
        L += kl_rows[j];
        C += custom_rows[j];
        int t = target[j];
        if (t != -1 && t != 0) Nn += 1.0f;    // valid & (tgt != PAD)
    }
    sl[tid] = L; sc[tid] = C; sn[tid] = Nn;
    __syncthreads();
    for (int s = 512; s > 0; s >>= 1) {
        if (tid < s) { sl[tid] += sl[tid+s]; sc[tid] += sc[tid+s]; sn[tid] += sn[tid+s]; }
        __syncthreads();
    }
    if (tid == 0) {
        float norm = sn[0];
        out[0] = sl[0] / norm + 0.1f * sc[0] / norm;
    }
}

extern "C" void kernel_launch(void* const* d_in, const int* in_sizes, int n_in,
                              void* d_out, int out_size, void* d_ws, size_t ws_size,
                              hipStream_t stream) {
    const float* X      = (const float*)d_in[0];   // (N, V) float32
    const int*   target = (const int*)d_in[1];     // (N,)   int32
    float*       out    = (float*)d_out;

    char* ws = (char*)d_ws;
    int*            ft32        = (int*)           (ws);                    // 128000 B
    unsigned short* ft16        = (unsigned short*)(ws + 128000);           //  64000 B
    float*          kl_rows     = (float*)         (ws + 192000);           //  16384 B
    float*          custom_rows = (float*)         (ws + 192000 + 16384);   //  16384 B

    k_init   <<<(VCOLS + 255) / 256, 256, 0, stream>>>(ft32);
    k_scatter<<<(NROWS + 255) / 256, 256, 0, stream>>>(target, ft32);
    k_pack   <<<(VCOLS + 255) / 256, 256, 0, stream>>>(ft32, ft16);
    k_main   <<<NROWS,               256, 0, stream>>>(X, target, ft16,
                                                       kl_rows, custom_rows);
    k_final  <<<1,                  1024, 0, stream>>>(kl_rows, custom_rows, target, out);
}